// Round 3
// baseline (978.574 us; speedup 1.0000x reference)
//
#include <hip/hip_runtime.h>

typedef short short8 __attribute__((ext_vector_type(8)));
typedef float floatx16 __attribute__((ext_vector_type(16)));
typedef float floatx4 __attribute__((ext_vector_type(4)));

#define ROWS 81
#define CDIM 256
#define QOFF 41472              // 81*512  (x tile, bf16, swizzled)
#define SOFF 62208              // QOFF + 81*256 (q tile, bf16, swizzled)
#define ABOFF 63232             // SOFF + 16*16*4 (scores f32)
#define SMEM_TOTAL 63744        // ABOFF + 16*32 (attn bf16)

__device__ __forceinline__ unsigned short f2bf(float f) {
    union { float f; unsigned int u; } v; v.f = f;
    return (unsigned short)((v.u + 0x7FFFu + ((v.u >> 16) & 1u)) >> 16);
}

__global__ void wconv_kernel(const float* __restrict__ W,
                             unsigned short* __restrict__ Wb, int n) {
    int i = blockIdx.x * 256 + threadIdx.x;
    if (i < n) Wb[i] = f2bf(W[i]);
}

__device__ __forceinline__ void stage_store(char* smem, int k, float4 a0, float4 a1) {
    int gr = k >> 5;
    int c0 = (k & 31) * 8;
    int hh = gr / 9, ww = gr - hh * 9;
    int r = ((hh / 3) * 3 + (ww / 3)) * 9 + ((hh % 3) * 3 + (ww % 3));
    short8 v;
    v[0] = (short)f2bf(a0.x); v[1] = (short)f2bf(a0.y);
    v[2] = (short)f2bf(a0.z); v[3] = (short)f2bf(a0.w);
    v[4] = (short)f2bf(a1.x); v[5] = (short)f2bf(a1.y);
    v[6] = (short)f2bf(a1.z); v[7] = (short)f2bf(a1.w);
    *(short8*)(smem + r * 512 + ((c0 * 2) ^ ((r & 15) << 4))) = v;
}

__global__ __launch_bounds__(512, 4)
void attn_kernel(const float* __restrict__ x,
                 const unsigned short* __restrict__ Wb,
                 const float* __restrict__ b_fc,
                 const int* __restrict__ block_idx,
                 const int* __restrict__ match_vec,
                 float* __restrict__ out,
                 int B, int nIter)
{
    __shared__ __align__(16) char smem[SMEM_TOTAL];
    const int t     = threadIdx.x;
    const int lane  = t & 63;
    const int wave  = t >> 6;       // 0..7
    const int l15   = lane & 15;
    const int kg    = lane >> 4;    // 0..3
    const int l31   = lane & 31;
    const int khalf = lane >> 5;    // 0..1
    const int base  = blockIdx.x * nIter;
    if (base >= B) return;

    // ---- once per block: W^T B-fragments + bias (L2-hot) ----
    short8 wfrag[8];
    {
        const unsigned short* wr = Wb + (wave * 16 + l15) * CDIM + kg * 8;
#pragma unroll
        for (int ks = 0; ks < 8; ++ks)
            wfrag[ks] = *(const short8*)(wr + ks * 32);
    }
    const float bias = b_fc[wave * 16 + l15];
    const int swl = l15 << 4;

    // ---- prologue: stage x[base] -> LDS (two half-batches, low reg peak) ----
    {
        const float* xb = x + (size_t)base * (ROWS * CDIM);
        float4 a0[3], a1[3];
#pragma unroll
        for (int j = 0; j < 3; ++j) {
            int k = t + 512 * j;
            a0[j] = *(const float4*)(xb + k * 8);
            a1[j] = *(const float4*)(xb + k * 8 + 4);
        }
#pragma unroll
        for (int j = 0; j < 3; ++j) stage_store(smem, t + 512 * j, a0[j], a1[j]);
#pragma unroll
        for (int j = 0; j < 2; ++j) {
            int k = t + 1536 + 512 * j;
            a0[j] = *(const float4*)(xb + k * 8);
            a1[j] = *(const float4*)(xb + k * 8 + 4);
        }
        if (t < 32) {
            a0[2] = *(const float4*)(xb + (t + 2560) * 8);
            a1[2] = *(const float4*)(xb + (t + 2560) * 8 + 4);
        }
#pragma unroll
        for (int j = 0; j < 2; ++j) stage_store(smem, t + 1536 + 512 * j, a0[j], a1[j]);
        if (t < 32) stage_store(smem, t + 2560, a0[2], a1[2]);
    }
    __syncthreads();

    for (int i = 0; base + i < B && i < nIter; ++i) {
        const int b = base + i;
        const bool hasNext = (i + 1 < nIter) && (b + 1 < B);
        const float* xn = x + (size_t)(b + 1) * (ROWS * CDIM);

        // ---- issue batch1 loads for b+1 (hidden under proj..epilogue) ----
        float4 n10[3], n11[3];
        if (hasNext) {
#pragma unroll
            for (int j = 0; j < 3; ++j) {
                int k = t + 512 * j;
                n10[j] = *(const float4*)(xn + k * 8);
                n11[j] = *(const float4*)(xn + k * 8 + 4);
            }
        }
        int cm = 0;
        if (t < 9) cm = match_vec[block_idx[b]];

        // ---- q[96x128] = x @ W^T via 16x16x32: 6 row-tiles x 8 ksteps ----
        {
            floatx4 acc[6];
#pragma unroll
            for (int ii = 0; ii < 6; ++ii)
#pragma unroll
                for (int j = 0; j < 4; ++j) acc[ii][j] = 0.f;
#pragma unroll
            for (int ks = 0; ks < 8; ++ks) {
                int cb = ks * 64 + kg * 16;
#pragma unroll
                for (int tile = 0; tile < 6; ++tile) {
                    int r = tile * 16 + l15;
                    short8 a = *(const short8*)(smem + r * 512 + (cb ^ swl));
                    acc[tile] = __builtin_amdgcn_mfma_f32_16x16x32_bf16(a, wfrag[ks], acc[tile], 0, 0, 0);
                }
            }
            int h2 = (wave * 16 + l15) * 2;
#pragma unroll
            for (int tile = 0; tile < 6; ++tile) {
#pragma unroll
                for (int reg = 0; reg < 4; ++reg) {
                    int r = tile * 16 + kg * 4 + reg;
                    if (r < ROWS)
                        *(unsigned short*)(smem + QOFF + r * 256 + (h2 ^ ((r & 15) << 4))) =
                            f2bf(acc[tile][reg] + bias);
                }
            }
        }
        __syncthreads();   // B: q ready

        // ---- issue batch2 loads for b+1 (7 waves otherwise idle here) ----
        float4 n20[2], n21[2], n30, n31;
        if (hasNext) {
#pragma unroll
            for (int j = 0; j < 2; ++j) {
                int k = t + 1536 + 512 * j;
                n20[j] = *(const float4*)(xn + k * 8);
                n21[j] = *(const float4*)(xn + k * 8 + 4);
            }
            if (t < 32) {
                n30 = *(const float4*)(xn + (t + 2560) * 8);
                n31 = *(const float4*)(xn + (t + 2560) * 8 + 4);
            }
        }

        // ---- scores = q_flat @ q_flat^T (wave 0, 4 interleaved chains) ----
        if (wave == 0) {
            floatx4 s0, s1, s2, s3;
#pragma unroll
            for (int ii = 0; ii < 4; ++ii) { s0[ii] = 0.f; s1[ii] = 0.f; s2[ii] = 0.f; s3[ii] = 0.f; }
            int nc = (l15 < 9) ? l15 : 8;
#pragma unroll
            for (int s = 0; s < 9; ++s) {
#pragma unroll
                for (int ii = 0; ii < 4; ++ii) {
                    int ks = ii * 9 + s;
                    int k  = ks * 32 + kg * 8;
                    int p  = k >> 7;
                    int h0 = (k & 127) * 2;
                    int row = nc * 9 + p;
                    short8 f = *(const short8*)(smem + QOFF + row * 256 + (h0 ^ ((row & 15) << 4)));
                    floatx4 tmp = __builtin_amdgcn_mfma_f32_16x16x32_bf16(
                        f, f, (ii == 0 ? s0 : ii == 1 ? s1 : ii == 2 ? s2 : s3), 0, 0, 0);
                    if (ii == 0) s0 = tmp; else if (ii == 1) s1 = tmp; else if (ii == 2) s2 = tmp; else s3 = tmp;
                }
            }
            float* sc = (float*)(smem + SOFF);
#pragma unroll
            for (int reg = 0; reg < 4; ++reg)
                sc[(kg * 4 + reg) * 16 + l15] = s0[reg] + s1[reg] + s2[reg] + s3[reg];
        }
        __syncthreads();   // C: scores ready

        // ---- masked softmax rows 0..8; attn bf16 [16][16] zero-padded ----
        if (t < 9) {
            const float scale = 0.029462782549439483f;   // (128*9)^-0.5
            float* sc = (float*)(smem + SOFF);
            float s[9];
            float mx = -1e30f;
#pragma unroll
            for (int m = 0; m < 9; ++m) {
                float v = sc[t * 16 + m] * scale;
                if (m == t && cm != 1) v -= 100.f;
                s[m] = v;
                mx = fmaxf(mx, v);
            }
            float sum = 0.f;
#pragma unroll
            for (int m = 0; m < 9; ++m) { s[m] = __expf(s[m] - mx); sum += s[m]; }
            float inv = 1.f / sum;
            unsigned short* ab = (unsigned short*)(smem + ABOFF) + t * 16;
#pragma unroll
            for (int m = 0; m < 9; ++m) ab[m] = f2bf(s[m] * inv);
#pragma unroll
            for (int m = 9; m < 16; ++m) ab[m] = 0;
        }
        __syncthreads();   // D: attn ready

        // ---- out^T = v^T @ attn^T via 32x32x16 MFMA; 9 d-tiles per wave ----
        {
            const int n  = l31;
            const int nm = (n < 9) ? n : 0;
            short8 bf = *(const short8*)(smem + ABOFF + nm * 32 + khalf * 16);
            float* ob = out + (size_t)b * (ROWS * CDIM);
            int hh = 0, ww = 0;
            if (n < 9) { hh = (n / 3) * 3; ww = (n % 3) * 3; }
#pragma unroll
            for (int tt = 0; tt < 9; ++tt) {
                int tile = wave * 9 + tt;
                int d = tile * 32 + l31;
                int p = d >> 8, c = d & 255;
                short8 af;
#pragma unroll
                for (int j = 0; j < 8; ++j) {
                    int m = khalf * 8 + j; if (m > 8) m = 8;   // m>8: B col is zero
                    int row = m * 9 + p;
                    af[j] = *(const short*)(smem + row * 512 + ((c * 2) ^ ((row & 15) << 4)));
                }
                floatx16 dacc;
#pragma unroll
                for (int ii = 0; ii < 16; ++ii) dacc[ii] = 0.f;
                dacc = __builtin_amdgcn_mfma_f32_32x32x16_bf16(af, bf, dacc, 0, 0, 0);
                if (n < 9) {
#pragma unroll
                    for (int q2 = 0; q2 < 4; ++q2) {
                        int d0 = tile * 32 + q2 * 8 + khalf * 4;
                        int p0 = d0 >> 8, c0 = d0 & 255;
                        int gr = (hh + (p0 / 3)) * 9 + (ww + (p0 % 3));
                        *(float4*)(ob + gr * CDIM + c0) =
                            make_float4(dacc[q2 * 4 + 0], dacc[q2 * 4 + 1],
                                        dacc[q2 * 4 + 2], dacc[q2 * 4 + 3]);
                    }
                }
            }
        }
        __syncthreads();   // E: all epilogue LDS reads done

        // ---- write b+1 staging regs -> LDS (vmcnt waits inserted here) ----
        if (hasNext) {
#pragma unroll
            for (int j = 0; j < 3; ++j) stage_store(smem, t + 512 * j, n10[j], n11[j]);
#pragma unroll
            for (int j = 0; j < 2; ++j) stage_store(smem, t + 1536 + 512 * j, n20[j], n21[j]);
            if (t < 32) stage_store(smem, t + 2560, n30, n31);
        }
        __syncthreads();   // A: x(b+1) ready
    }
}

extern "C" void kernel_launch(void* const* d_in, const int* in_sizes, int n_in,
                              void* d_out, int out_size, void* d_ws, size_t ws_size,
                              hipStream_t stream) {
    const float* x    = (const float*)d_in[0];
    const float* W    = (const float*)d_in[1];
    const float* bfc  = (const float*)d_in[2];
    const int*   bidx = (const int*)d_in[3];
    const int*   mvec = (const int*)d_in[4];
    float* outp = (float*)d_out;
    unsigned short* Wb = (unsigned short*)d_ws;

    int nW = in_sizes[1];                       // 128*256
    wconv_kernel<<<(nW + 255) / 256, 256, 0, stream>>>(W, Wb, nW);

    int B = in_sizes[0] / (ROWS * CDIM);        // 8192
    int grid = (B >= 512) ? 512 : B;
    int nIter = (B + grid - 1) / grid;          // 16
    attn_kernel<<<grid, 512, 0, stream>>>(x, Wb, bfc, bidx, mvec, outp, B, nIter);
}

// Round 4
// 417.280 us; speedup vs baseline: 2.3451x; 2.3451x over previous
//
#include <hip/hip_runtime.h>

typedef short short8 __attribute__((ext_vector_type(8)));
typedef float floatx16 __attribute__((ext_vector_type(16)));
typedef float floatx4 __attribute__((ext_vector_type(4)));

#define ROWS 81
#define CDIM 256
// LDS layout (total 53376 B -> 3 blocks/CU on 160 KB LDS)
#define XT   0          // x tile bf16 [81][256], p-major rows, swizzle (r&15)<<4, stride 512B
#define QH   41472      // q half bf16 [81][64],  swizzle (r&7)<<4,  stride 128B
#define SC   51840      // scores f32 [16][16]
#define AB   52864      // attn bf16 [16][16] (rows 9..15 unwritten, cols 9..15 zeroed)
#define TOT  53376

__device__ __forceinline__ unsigned short f2bf(float f) {
    union { float f; unsigned int u; } v; v.f = f;
    return (unsigned short)((v.u + 0x7FFFu + ((v.u >> 16) & 1u)) >> 16);
}

__global__ void wconv_kernel(const float* __restrict__ W,
                             unsigned short* __restrict__ Wb, int n) {
    int i = blockIdx.x * 256 + threadIdx.x;
    if (i < n) Wb[i] = f2bf(W[i]);
}

__global__ __launch_bounds__(512, 6)
void attn_kernel(const float* __restrict__ x,
                 const unsigned short* __restrict__ Wb,
                 const float* __restrict__ b_fc,
                 const int* __restrict__ block_idx,
                 const int* __restrict__ match_vec,
                 float* __restrict__ out)
{
    __shared__ __align__(16) char smem[TOT];
    const int b     = blockIdx.x;
    const int t     = threadIdx.x;
    const int lane  = t & 63;
    const int wave  = t >> 6;       // 0..7
    const int l15   = lane & 15;
    const int kg    = lane >> 4;    // 0..3
    const int l31   = lane & 31;
    const int khalf = lane >> 5;    // 0..1

    int cm = 0;
    if (t < 9) cm = match_vec[block_idx[b]];

    // ---- W^T B-fragments (wave's 16 h-cols; L2-hot) ----
    short8 wfrag[8];
    {
        const unsigned short* wr = Wb + (wave * 16 + l15) * CDIM + kg * 8;
#pragma unroll
        for (int ks = 0; ks < 8; ++ks)
            wfrag[ks] = *(const short8*)(wr + ks * 32);
    }
    const float bias = b_fc[wave * 16 + l15];

    // ---- zero scores accumulator ----
    if (t < 256) ((float*)(smem + SC))[t] = 0.f;

    // ---- stage x -> LDS bf16, p-major rows (r = p*9+m), XOR-swizzled ----
    {
        const float* xb = x + (size_t)b * (ROWS * CDIM);
        for (int k = t; k < ROWS * 32; k += 512) {
            int gr = k >> 5;
            int c0 = (k & 31) * 8;
            float4 a0 = *(const float4*)(xb + gr * CDIM + c0);
            float4 a1 = *(const float4*)(xb + gr * CDIM + c0 + 4);
            int hh = gr / 9, ww = gr - hh * 9;
            int p = (hh % 3) * 3 + (ww % 3);
            int m = (hh / 3) * 3 + (ww / 3);
            int r = p * 9 + m;
            short8 v;
            v[0] = (short)f2bf(a0.x); v[1] = (short)f2bf(a0.y);
            v[2] = (short)f2bf(a0.z); v[3] = (short)f2bf(a0.w);
            v[4] = (short)f2bf(a1.x); v[5] = (short)f2bf(a1.y);
            v[6] = (short)f2bf(a1.z); v[7] = (short)f2bf(a1.w);
            *(short8*)(smem + XT + r * 512 + ((c0 * 2) ^ ((r & 15) << 4))) = v;
        }
    }
    __syncthreads();

    // ---- projection q[96x128] = x @ W^T : 6 row-tiles x 8 k-steps ----
    floatx4 acc[6];
#pragma unroll
    for (int i = 0; i < 6; ++i)
#pragma unroll
        for (int j = 0; j < 4; ++j) acc[i][j] = 0.f;
    const int swl = l15 << 4;
#pragma unroll
    for (int ks = 0; ks < 8; ++ks) {
        int cb = ks * 64 + kg * 16;
#pragma unroll
        for (int tile = 0; tile < 6; ++tile) {
            int r = tile * 16 + l15;
            short8 a = *(const short8*)(smem + XT + r * 512 + (cb ^ swl));
            acc[tile] = __builtin_amdgcn_mfma_f32_16x16x32_bf16(a, wfrag[ks], acc[tile], 0, 0, 0);
        }
    }

    // ---- q half 1 (h 0..63): waves 0..3 write their slice ----
    if (wave < 4) {
        int h2 = (wave * 16 + l15) * 2;
#pragma unroll
        for (int tile = 0; tile < 6; ++tile)
#pragma unroll
            for (int reg = 0; reg < 4; ++reg) {
                int r = tile * 16 + kg * 4 + reg;
                if (r < ROWS)
                    *(unsigned short*)(smem + QH + r * 128 + (h2 ^ ((r & 7) << 4))) =
                        f2bf(acc[tile][reg] + bias);
            }
    }
    __syncthreads();

    // ---- partial Gram over the current q-half (all 8 waves) ----
    const int nc = (l15 < 9) ? l15 : 8;
#define GRAM_HALF()                                                                 \
    {                                                                               \
        floatx4 g; g[0] = 0.f; g[1] = 0.f; g[2] = 0.f; g[3] = 0.f;                  \
        for (int ks = wave; ks < 18; ks += 8) {                                     \
            int p  = ks >> 1;                                                       \
            int h0 = (ks & 1) * 64 + kg * 16;      /* byte offset of h chunk */     \
            int row = p * 9 + nc;                                                   \
            short8 f = *(const short8*)(smem + QH + row * 128 +                     \
                                        (h0 ^ ((row & 7) << 4)));                   \
            g = __builtin_amdgcn_mfma_f32_16x16x32_bf16(f, f, g, 0, 0, 0);          \
        }                                                                           \
        float* sc = (float*)(smem + SC);                                            \
        _Pragma("unroll")                                                           \
        for (int reg = 0; reg < 4; ++reg)                                           \
            atomicAdd(&sc[(kg * 4 + reg) * 16 + l15], g[reg]);                      \
    }
    GRAM_HALF();
    __syncthreads();

    // ---- q half 2 (h 64..127): waves 4..7 overwrite the slice ----
    if (wave >= 4) {
        int h2 = ((wave - 4) * 16 + l15) * 2;
#pragma unroll
        for (int tile = 0; tile < 6; ++tile)
#pragma unroll
            for (int reg = 0; reg < 4; ++reg) {
                int r = tile * 16 + kg * 4 + reg;
                if (r < ROWS)
                    *(unsigned short*)(smem + QH + r * 128 + (h2 ^ ((r & 7) << 4))) =
                        f2bf(acc[tile][reg] + bias);
            }
    }
    __syncthreads();
    GRAM_HALF();
    __syncthreads();

    // ---- masked softmax rows 0..8; attn bf16 [16][16], cols 9..15 zeroed ----
    if (t < 9) {
        const float scale = 0.029462782549439483f;   // (128*9)^-0.5
        float* sc = (float*)(smem + SC);
        float s[9];
        float mx = -1e30f;
#pragma unroll
        for (int m = 0; m < 9; ++m) {
            float v = sc[t * 16 + m] * scale;
            if (m == t && cm != 1) v -= 100.f;
            s[m] = v;
            mx = fmaxf(mx, v);
        }
        float sum = 0.f;
#pragma unroll
        for (int m = 0; m < 9; ++m) { s[m] = __expf(s[m] - mx); sum += s[m]; }
        float inv = 1.f / sum;
        unsigned short* ab = (unsigned short*)(smem + AB) + t * 16;
#pragma unroll
        for (int m = 0; m < 9; ++m) ab[m] = f2bf(s[m] * inv);
#pragma unroll
        for (int m = 9; m < 16; ++m) ab[m] = 0;
    }
    __syncthreads();

    // ---- out^T = v^T @ attn^T via 32x32x16; 9 d-tiles/wave; p-major af ----
    {
        const int n  = l31;
        const int nm = (n < 9) ? n : 0;
        short8 bf = *(const short8*)(smem + AB + nm * 32 + khalf * 16);
        float* ob = out + (size_t)b * (ROWS * CDIM);
        int hh0 = 0, ww0 = 0;
        if (n < 9) { hh0 = (n / 3) * 3; ww0 = (n % 3) * 3; }
#pragma unroll
        for (int tt = 0; tt < 9; ++tt) {
            int tile = wave * 9 + tt;
            int d = tile * 32 + l31;
            int p = d >> 8, c = d & 255;
            short8 af;
#pragma unroll
            for (int j = 0; j < 8; ++j) {
                int mm = khalf * 8 + j; if (mm > 8) mm = 8;   // m>8: attn col is 0
                int row = p * 9 + mm;                          // consecutive rows
                af[j] = *(const short*)(smem + XT + row * 512 + ((c * 2) ^ ((row & 15) << 4)));
            }
            floatx16 dacc;
#pragma unroll
            for (int i = 0; i < 16; ++i) dacc[i] = 0.f;
            dacc = __builtin_amdgcn_mfma_f32_32x32x16_bf16(af, bf, dacc, 0, 0, 0);
            if (n < 9) {
#pragma unroll
                for (int q2 = 0; q2 < 4; ++q2) {
                    int d0 = tile * 32 + q2 * 8 + khalf * 4;
                    int p0 = d0 >> 8, c0 = d0 & 255;
                    int gr = (hh0 + p0 / 3) * 9 + (ww0 + p0 % 3);
                    *(float4*)(ob + gr * CDIM + c0) =
                        make_float4(dacc[q2 * 4 + 0], dacc[q2 * 4 + 1],
                                    dacc[q2 * 4 + 2], dacc[q2 * 4 + 3]);
                }
            }
        }
    }
}

extern "C" void kernel_launch(void* const* d_in, const int* in_sizes, int n_in,
                              void* d_out, int out_size, void* d_ws, size_t ws_size,
                              hipStream_t stream) {
    const float* x    = (const float*)d_in[0];
    const float* W    = (const float*)d_in[1];
    const float* bfc  = (const float*)d_in[2];
    const int*   bidx = (const int*)d_in[3];
    const int*   mvec = (const int*)d_in[4];
    float* outp = (float*)d_out;
    unsigned short* Wb = (unsigned short*)d_ws;

    int nW = in_sizes[1];                       // 128*256
    wconv_kernel<<<(nW + 255) / 256, 256, 0, stream>>>(W, Wb, nW);

    int B = in_sizes[0] / (ROWS * CDIM);        // 8192
    attn_kernel<<<B, 512, 0, stream>>>(x, Wb, bfc, bidx, mvec, outp);
}